// Round 13
// baseline (208.908 us; speedup 1.0000x reference)
//
#include <hip/hip_runtime.h>
#include <stdint.h>

// SSIM loss — fused separable box filter. R13: deep LDS row-ring.
// Every kernel R5-R12 ran at FETCH/~2.5TB/s with all pipes idle; R12 proved
// prefetch distance doesn't help (compiler emits conservative vmcnt(0) at
// ds_read of DMA'd slots). So: (a) halve vmem — each row is DMA'd ONCE into a
// 14-slot LDS ring and read twice from LDS (add at ro=r-5, sub at ro=r+5;
// no global sub re-read); (b) DMA issued 3 rows (~3k cyc) ahead of its
// consumer, so even a full vmcnt(0) drain waits on nothing; (c) warm-up
// batch-issues 13 row DMAs (52KB in flight) -> one exposed latency.
//
// Grid: 512 blocks = 64 images x 8 strips; block = 1 wave (64 threads) owns
// SH=64 rows x 512 cols (lane owns 8 cols). LDS 56KB/block -> exactly
// 2 blocks/CU (112 <= 160KB), matching the 512-block grid. Horizontal 11-col
// window via DPP wave shifts (bound_ctrl zero-fill = image-border zeros).

#define IMG_H 512
#define IMG_W 512
#define N_IMG 64
#define RAD   5
#define SH    64
#define NSTRIP 8                    // strips per image
#define NBLOCKS (N_IMG * NSTRIP)    // 512

#define C1_SSIM 1.0e-4f
#define C2_SSIM 9.0e-4f

#define SLOT_BYTES 4096             // x row (2048 B) + y row (2048 B)
#define RING_SLOTS 14
#define RING_BYTES (RING_SLOTS * SLOT_BYTES)   // 57344

typedef __attribute__((address_space(3))) uint32_t lds_u32_t;
typedef const __attribute__((address_space(1))) uint32_t glb_u32_t;

__device__ __forceinline__ void dma16(void* lds, const void* g) {
    // 64 lanes x 16 B: LDS dest = wave-uniform base + lane*16 (m104/m108)
    __builtin_amdgcn_global_load_lds((glb_u32_t*)g, (lds_u32_t*)lds, 16, 0, 0);
}

// lane n <- lane n-1, lane 0 <- 0   (DPP wave_shr:1, bound_ctrl zero-fill)
__device__ __forceinline__ float dpp_up1(float v) {
    int r = __builtin_amdgcn_update_dpp(0, __float_as_int(v), 0x138, 0xf, 0xf, true);
    return __int_as_float(r);
}
// lane n <- lane n+1, lane 63 <- 0  (DPP wave_shl:1, bound_ctrl zero-fill)
__device__ __forceinline__ float dpp_dn1(float v) {
    int r = __builtin_amdgcn_update_dpp(0, __float_as_int(v), 0x130, 0xf, 0xf, true);
    return __int_as_float(r);
}

__global__ __launch_bounds__(64) void ssim_fused(const float* __restrict__ x,
                                                 const float* __restrict__ y,
                                                 float* __restrict__ part)
{
    __shared__ __align__(16) char ring[RING_BYTES];

    const int tx  = threadIdx.x;                // single wave: lane id
    const int img = blockIdx.x >> 3;            // / NSTRIP
    const int st  = blockIdx.x & (NSTRIP - 1);
    const int r0  = st * SH;

    const float* __restrict__ xi = x + (size_t)img * (IMG_H * IMG_W);
    const float* __restrict__ yi = y + (size_t)img * (IMG_H * IMG_W);

    // DMA one (x,y) row pair into the slot at byte offset so. Caller
    // guarantees 0 <= ri < IMG_H (skipped rows are never read back).
    auto dma_row = [&](int so, int ri) {
        const char* xg = (const char*)(xi + (size_t)ri * IMG_W) + tx * 16;
        const char* yg = (const char*)(yi + (size_t)ri * IMG_W) + tx * 16;
        char* s = ring + so;
        dma16(s,        xg);
        dma16(s + 1024, xg + 1024);
        dma16(s + 2048, yg);
        dma16(s + 3072, yg + 1024);
    };

    float Vx[8], Vy[8], Vxx[8], Vyy[8], Vxy[8];
#pragma unroll
    for (int j = 0; j < 8; ++j) { Vx[j] = 0.f; Vy[j] = 0.f; Vxx[j] = 0.f; Vyy[j] = 0.f; Vxy[j] = 0.f; }

    // read the staged row at slot offset so and add (add=true) or subtract it
    // from the running vertical moment sums
    auto accum_lds = [&](int so, bool add) {
        const float4* xr = (const float4*)(ring + so + (size_t)tx * 32);
        const float4* yr = (const float4*)(ring + so + 2048 + (size_t)tx * 32);
        float4 x0 = xr[0], x1 = xr[1];
        float4 y0 = yr[0], y1 = yr[1];
        float xs[8] = {x0.x, x0.y, x0.z, x0.w, x1.x, x1.y, x1.z, x1.w};
        float ys[8] = {y0.x, y0.y, y0.z, y0.w, y1.x, y1.y, y1.z, y1.w};
        if (add) {
#pragma unroll
            for (int j = 0; j < 8; ++j) {
                Vx[j]  += xs[j];
                Vy[j]  += ys[j];
                Vxx[j] = fmaf(xs[j], xs[j], Vxx[j]);
                Vyy[j] = fmaf(ys[j], ys[j], Vyy[j]);
                Vxy[j] = fmaf(xs[j], ys[j], Vxy[j]);
            }
        } else {
#pragma unroll
            for (int j = 0; j < 8; ++j) {
                Vx[j]  -= xs[j];
                Vy[j]  -= ys[j];
                Vxx[j] = fmaf(-xs[j], xs[j], Vxx[j]);
                Vyy[j] = fmaf(-ys[j], ys[j], Vyy[j]);
                Vxy[j] = fmaf(-xs[j], ys[j], Vxy[j]);
            }
        }
    };

    // 11-tap sliding horizontal sums; halo via DPP wave shifts
    auto hsum = [&](const float (&V)[8], float (&S)[8]) {
        float w[18];
#pragma unroll
        for (int k = 0; k < 5; ++k) w[k] = dpp_up1(V[3 + k]);   // lane-1's V[3..7]
#pragma unroll
        for (int j = 0; j < 8; ++j) w[5 + j] = V[j];
#pragma unroll
        for (int k = 0; k < 5; ++k) w[13 + k] = dpp_dn1(V[k]);  // lane+1's V[0..4]
        float s = 0.f;
#pragma unroll
        for (int t = 0; t < 11; ++t) s += w[t];
        S[0] = s;
#pragma unroll
        for (int j = 1; j < 8; ++j) { s += w[j + 10] - w[j - 1]; S[j] = s; }
    };

    // ---- warm-up: batch-issue 13 row DMAs (rows r0-5 .. r0+7 -> slots 0..12),
    // then accumulate rows r0-5 .. r0+4 from LDS (one exposed drain) ----
#pragma unroll
    for (int i = 0; i < 13; ++i) {
        int ri = r0 - 5 + i;
        if (ri >= 0 && ri < IMG_H) dma_row(i * SLOT_BYTES, ri);
    }
#pragma unroll 1
    for (int i = 0; i < 10; ++i) {
        int ri = r0 - 5 + i;                     // <= 452, always < IMG_H
        if (ri >= 0) accum_lds(i * SLOT_BYTES, true);
    }

    // slot offsets at ro = r0: sub row ro-5 -> slot 0; add row ro+5 -> slot 10;
    // DMA row ro+8 -> slot 13. All advance by one slot per row (mod 14).
    int subOff = 0;
    int addOff = 10 * SLOT_BYTES;
    int dmaOff = 13 * SLOT_BYTES;

    const float inv121 = 1.0f / 121.0f;
    float loss = 0.0f;

#pragma unroll 1
    for (int ro = r0; ro < r0 + SH; ++ro) {
        // add row ro+5 (DMA'd 3 rows ago — any vmcnt drain here waits on
        // nothing newer than ~3k cycles old)
        if (ro + RAD < IMG_H) accum_lds(addOff, true);

        // distance-3 prefetch; rows past r0+SH+4 are never consumed -> skip
        int rd = ro + 8;
        if (rd < IMG_H && rd <= r0 + SH + 4) dma_row(dmaOff, rd);

        float Sx[8], Sy[8], Sxx[8], Syy[8], Sxy[8];
        hsum(Vx,  Sx);
        hsum(Vy,  Sy);
        hsum(Vxx, Sxx);
        hsum(Vyy, Syy);
        hsum(Vxy, Sxy);

#pragma unroll
        for (int j = 0; j < 8; ++j) {
            float mx  = Sx[j] * inv121;
            float my  = Sy[j] * inv121;
            float mx2 = mx * mx;
            float my2 = my * my;
            float mxy = mx * my;
            float vx  = Sxx[j] * inv121 - mx2;
            float vy  = Syy[j] * inv121 - my2;
            float vxy = Sxy[j] * inv121 - mxy;
            float num = (2.0f * mxy + C1_SSIM) * (2.0f * vxy + C2_SSIM);
            float den = (mx2 + my2 + C1_SSIM) * (vx + vy + C2_SSIM);
            loss += __fdividef(num, den);
        }

        // subtract row ro-5 — from the ring (LDS), NOT a global re-read
        if (ro - RAD >= 0) accum_lds(subOff, false);

        subOff += SLOT_BYTES; if (subOff == RING_BYTES) subOff = 0;
        addOff += SLOT_BYTES; if (addOff == RING_BYTES) addOff = 0;
        dmaOff += SLOT_BYTES; if (dmaOff == RING_BYTES) dmaOff = 0;
    }

    // single-wave block: shfl-reduce, lane 0 stores the block partial
#pragma unroll
    for (int off = 32; off > 0; off >>= 1)
        loss += __shfl_down(loss, off, 64);
    if (tx == 0) part[blockIdx.x] = loss;
}

// single-block finisher: reduce 512 partials (2 KB) and write the loss
__global__ __launch_bounds__(256) void ssim_reduce(const float* __restrict__ part,
                                                   float* __restrict__ out)
{
    const int t  = threadIdx.x;
    const int tx = t & 63;
    float s = part[t] + part[t + 256];
#pragma unroll
    for (int off = 32; off > 0; off >>= 1)
        s += __shfl_down(s, off, 64);
    __shared__ float ws[4];
    if (tx == 0) ws[t >> 6] = s;
    __syncthreads();
    if (t == 0) {
        float total = (ws[0] + ws[1]) + (ws[2] + ws[3]);
        out[0] = 1.0f - total * (1.0f / ((float)N_IMG * IMG_H * IMG_W));
    }
}

extern "C" void kernel_launch(void* const* d_in, const int* in_sizes, int n_in,
                              void* d_out, int out_size, void* d_ws, size_t ws_size,
                              hipStream_t stream) {
    const float* x = (const float*)d_in[0];
    const float* y = (const float*)d_in[1];
    // d_in[2] is the uniform 11x11/121 kernel; its value is compile-time known.
    float* part = (float*)d_ws;            // 512 floats, all written each call

    ssim_fused<<<NBLOCKS, 64, 0, stream>>>(x, y, part);
    ssim_reduce<<<1, 256, 0, stream>>>(part, (float*)d_out);
}